// Round 1
// 202.206 us; speedup vs baseline: 1.0368x; 1.0368x over previous
//
#include <hip/hip_runtime.h>
#include <hip/hip_bf16.h>

#define N_NODES 50000
#define N_EDGES 800000
#define D 64
#define B 64
#define HL 128
#define OUT 32

#define CAP 64          // max in-degree capacity (Poisson(16): P(>=64) ~ 1e-18)
#define STP 72          // LDS transform tile row stride (ushorts)
#define ZROW N_NODES    // sentinel index (u16-safe: 50000 < 65536)

#define BINS 196        // ceil(N_NODES/256): coarse bins of 256 nodes (dst>>8)
#define EPB 2048        // edges per block in binA
#define LCAP 48         // per-(block,bin) LDS staging cap
#define BCAP 4608       // per-bin global region cap (mean 4082)

#define AB 391          // binA blocks
#define CB 3125         // cvt blocks (N*D/4/256)

typedef __attribute__((ext_vector_type(8))) short          short8;
typedef __attribute__((ext_vector_type(8))) unsigned short ushort8_t;
typedef __attribute__((ext_vector_type(4))) float          floatx4;

// bf16 helpers (RNE pack, cheap unpack)
__device__ __forceinline__ unsigned short f2bf(float f)
{
    unsigned u = __float_as_uint(f);
    u = (u + 0x7FFFu + ((u >> 16) & 1u)) >> 16;
    return (unsigned short)u;
}
__device__ __forceinline__ float bf2f(unsigned short s)
{
    return __uint_as_float(((unsigned)s) << 16);
}
// packed-dword bf16 unpack: lo element = u<<16, hi element = u&0xffff0000
__device__ __forceinline__ float bfLO(unsigned u) { return __uint_as_float(u << 16); }
__device__ __forceinline__ float bfHI(unsigned u) { return __uint_as_float(u & 0xffff0000u); }

// ---------------------------------------------------------------------------
// Fused prologue, block-range roles (independent work overlaps in 1 dispatch):
//   [0, AB)        : binA — bin edges by dst>>8 via LDS staging
//   [AB, AB+CB)    : cvt x -> bf16 (first 64 also convert MLP weights)
//   AB+CB          : init — sentinel zero rows + psum zero
// bincnt is zeroed by a prior 1KB memset.
// ---------------------------------------------------------------------------
__global__ __launch_bounds__(256) void fused_pro_kernel(
    const int*   __restrict__ ei,
    int*         __restrict__ bincnt,
    unsigned*    __restrict__ binbuf,
    const float* __restrict__ x, unsigned short* __restrict__ xb,
    const float* __restrict__ w1, const float* __restrict__ w2,
    const float* __restrict__ w3, const float* __restrict__ w4,
    unsigned short* __restrict__ wb,
    unsigned short* __restrict__ h1,
    float*       __restrict__ psum)
{
    __shared__ int      lcnt[BINS];
    __shared__ int      gbase[BINS];
    __shared__ unsigned lbuf[BINS * LCAP];   // 37.6 KB

    int t = threadIdx.x;

    if (blockIdx.x < AB) {
        // ---------------- binA ----------------
        if (t < BINS) lcnt[t] = 0;
        __syncthreads();

        int base = blockIdx.x * EPB;
#pragma unroll
        for (int i = 0; i < EPB / 256; ++i) {
            int e = base + i * 256 + t;
            if (e < N_EDGES) {
                int s = ei[e];
                int d = ei[N_EDGES + e];
                int bin = d >> 8;
                unsigned pk = (unsigned)s | ((unsigned)(d & 255) << 16);
                int p = atomicAdd(&lcnt[bin], 1);
                if (p < LCAP) {
                    lbuf[bin * LCAP + p] = pk;
                } else {                          // statistically never
                    int q = atomicAdd(&bincnt[bin], 1);
                    if (q < BCAP) binbuf[bin * BCAP + q] = pk;
                }
            }
        }
        __syncthreads();

        if (t < BINS) {
            int m = lcnt[t]; m = (m < LCAP) ? m : LCAP;
            gbase[t] = (m > 0) ? atomicAdd(&bincnt[t], m) : 0;
        }
        __syncthreads();

        int wv = t >> 6, lane = t & 63;
        for (int b = wv; b < BINS; b += 4) {
            int m = lcnt[b]; m = (m < LCAP) ? m : LCAP;
            int gb = gbase[b];
            for (int j = lane; j < m; j += 64)
                if (gb + j < BCAP) binbuf[b * BCAP + gb + j] = lbuf[b * LCAP + j];
        }
    } else if (blockIdx.x < AB + CB) {
        // ---------------- cvt ----------------
        int cb = blockIdx.x - AB;
        int i = cb * 256 + t;                    // i < N*D/4
        const float4 v = reinterpret_cast<const float4*>(x)[i];
        ushort4 o;
        o.x = f2bf(v.x); o.y = f2bf(v.y); o.z = f2bf(v.z); o.w = f2bf(v.w);
        reinterpret_cast<ushort4*>(xb)[i] = o;

        if (cb < 64) {                           // 64*256 = 4*4096
            int j = cb * 256 + t;
            int m = j >> 12, off = j & 4095;
            const float* src = (m == 0) ? w1 : (m == 1) ? w2 : (m == 2) ? w3 : w4;
            wb[j] = f2bf(src[off]);
        }
    } else {
        // ---------------- init ----------------
        if (t < D) {                             // sentinel zero rows
            xb[(size_t)ZROW * D + t] = 0;
            h1[(size_t)ZROW * D + t] = 0;
        }
#pragma unroll
        for (int k = 0; k < 16; ++k)             // psum[B*64] = 0
            psum[t * 16 + k] = 0.0f;
    }
}

// ---------------------------------------------------------------------------
// Adjacency build phase B: block per bin (256 nodes). LDS rows pre-filled
// with sentinel ZROW so bucket rows are padded -> branchless gather.
// ---------------------------------------------------------------------------
__global__ __launch_bounds__(256) void binB_kernel(
    const int*      __restrict__ bincnt,
    const unsigned* __restrict__ binbuf,
    int*            __restrict__ cnt,     // [N]
    unsigned short* __restrict__ bucket)  // [N,CAP]
{
    __shared__ int            lc[256];
    __shared__ unsigned short lbkt[256 * CAP];   // 32 KB

    int t = threadIdx.x;
    lc[t] = 0;
    {
        ushort8_t fill = {ZROW, ZROW, ZROW, ZROW, ZROW, ZROW, ZROW, ZROW};
        for (int idx = t; idx < 256 * CAP / 8; idx += 256)
            reinterpret_cast<ushort8_t*>(lbkt)[idx] = fill;
    }
    __syncthreads();

    int bin = blockIdx.x;
    int m = bincnt[bin]; m = (m < BCAP) ? m : BCAP;
    const unsigned* src = binbuf + bin * BCAP;
    for (int j = t; j < m; j += 256) {
        unsigned pk = src[j];
        int dlow = (pk >> 16) & 255;
        int p = atomicAdd(&lc[dlow], 1);
        if (p < CAP) lbkt[dlow * CAP + p] = (unsigned short)(pk & 0xFFFFu);
    }
    __syncthreads();

    int n0 = bin * 256;
    int n = n0 + t;
    if (n < N_NODES) cnt[n] = (lc[t] < CAP) ? lc[t] : CAP;

    for (int idx = t; idx < 256 * 8; idx += 256) {
        int r = idx >> 3, c = idx & 7;
        if (n0 + r < N_NODES)
            *reinterpret_cast<ushort8_t*>(
                bucket + (size_t)(n0 + r) * CAP + c * 8) =
                *reinterpret_cast<const ushort8_t*>(&lbkt[r * CAP + c * 8]);
    }
}

// ---------------------------------------------------------------------------
// In-kernel gather of a wave's 16-node tile into its LDS transform tile.
// Wave processes 4 nodes at a time: group g = lane>>4 owns node n0+b*4+g,
// lane c = lane&15 owns dims 4c..4c+3. Neighbor rows are loaded as uint2
// (8 B/lane, 512 B per VMEM instruction across the 4 groups) — 4x fewer
// VMEM instructions than the old 2 B/lane wave-per-node gather. Rounds of
// 8 rows; buckets are ZROW-padded so overshoot rows add cached zeros.
// Loop trip = max over the 4 groups (shfl-xor max) -> wave-uniform.
// ---------------------------------------------------------------------------
__device__ __forceinline__ void gather16(
    const unsigned short* __restrict__ feat,
    const int*            __restrict__ cnt,
    const unsigned short* __restrict__ bucket,
    unsigned short*       stw,            // wave's LDS tile, 16 rows x STP
    int n0, int lane)
{
    const int g = lane >> 4;
    const int c = lane & 15;

#pragma unroll
    for (int b = 0; b < 4; ++b) {
        const int node = n0 + b * 4 + g;
        int deg = cnt[node];
        deg = (deg < CAP) ? deg : CAP;
        int m = (deg + 7) >> 3;
        {   // wave-max over the 4 groups
            int t1 = __shfl_xor(m, 16); m = (t1 > m) ? t1 : m;
            int t2 = __shfl_xor(m, 32); m = (t2 > m) ? t2 : m;
        }

        const unsigned short* bkt = bucket + (size_t)node * CAP;

        // self row
        uint2 u = *reinterpret_cast<const uint2*>(feat + (size_t)node * D + 4 * c);
        float a0 = bfLO(u.x), a1 = bfHI(u.x);
        float a2 = bfLO(u.y), a3 = bfHI(u.y);

        // software-pipelined index loads (16 B, uniform within group);
        // reading one ushort8 past row end lands in adjacent ws (safe, unused)
        ushort8_t idx = *reinterpret_cast<const ushort8_t*>(bkt);
        for (int r = 0; r < m; ++r) {
            ushort8_t nxt = *reinterpret_cast<const ushort8_t*>(bkt + (r + 1) * 8);
#pragma unroll
            for (int j = 0; j < 8; ++j) {
                uint2 v = *reinterpret_cast<const uint2*>(
                    feat + (size_t)idx[j] * D + 4 * c);
                a0 += bfLO(v.x); a1 += bfHI(v.x);
                a2 += bfLO(v.y); a3 += bfHI(v.y);
            }
            idx = nxt;
        }

        uint2 o;
        o.x = (unsigned)f2bf(a0) | ((unsigned)f2bf(a1) << 16);
        o.y = (unsigned)f2bf(a2) | ((unsigned)f2bf(a3) << 16);
        *reinterpret_cast<uint2*>(stw + (b * 4 + g) * STP + 4 * c) = o;
    }
}

// ---------------------------------------------------------------------------
// Fused gather + MLP layer 1 via MFMA (verified m89/m91 layouts).
// Gather writes the wave's A-tile into LDS; MFMA A-fragments are read from
// LDS (same pattern as the T transpose reads). No barriers: tiles are
// per-wave, so waves in the MFMA phase hide other waves' gather latency.
// ---------------------------------------------------------------------------
__global__ __launch_bounds__(256) void gmlp_kernel(
    const unsigned short* __restrict__ feat,   // node features (bf16 rows)
    const int*            __restrict__ cnt,
    const unsigned short* __restrict__ bucket,
    const unsigned short* __restrict__ wAb,
    const float*          __restrict__ bA,
    const unsigned short* __restrict__ wBb,
    const float*          __restrict__ bB,
    unsigned short*       __restrict__ outp)
{
    __shared__ __align__(16) unsigned short st[4][16 * STP];

    const int wv   = threadIdx.x >> 6;
    const int lane = threadIdx.x & 63;
    const int quad = lane >> 4;
    const int col  = lane & 15;

    const int n0 = (blockIdx.x * 4 + wv) * 16;
    if (n0 >= N_NODES) return;

    float bAl[4], bBl[4];
#pragma unroll
    for (int t = 0; t < 4; ++t) {
        bAl[t] = bA[t * 16 + col];
        bBl[t] = bB[t * 16 + col];
    }

    short8 WA[4][2], WB[4][2];
#pragma unroll
    for (int t = 0; t < 4; ++t)
#pragma unroll
        for (int k = 0; k < 2; ++k) {
            WA[t][k] = *reinterpret_cast<const short8*>(
                wAb + (t * 16 + col) * D + k * 32 + quad * 8);
            WB[t][k] = *reinterpret_cast<const short8*>(
                wBb + (t * 16 + col) * D + k * 32 + quad * 8);
        }

    unsigned short* stw = &st[wv][0];

    gather16(feat, cnt, bucket, stw, n0, lane);

    short8 A0 = *reinterpret_cast<const short8*>(stw + col * STP + 0 * 32 + quad * 8);
    short8 A1 = *reinterpret_cast<const short8*>(stw + col * STP + 1 * 32 + quad * 8);

#pragma unroll
    for (int t = 0; t < 4; ++t) {
        floatx4 c = {0.0f, 0.0f, 0.0f, 0.0f};
        c = __builtin_amdgcn_mfma_f32_16x16x32_bf16(A0, WA[t][0], c, 0, 0, 0);
        c = __builtin_amdgcn_mfma_f32_16x16x32_bf16(A1, WA[t][1], c, 0, 0, 0);
#pragma unroll
        for (int r = 0; r < 4; ++r) {
            float v = fmaxf(c[r] + bAl[t], 0.0f);
            stw[(quad * 4 + r) * STP + t * 16 + col] = f2bf(v);
        }
    }

    short8 T0 = *reinterpret_cast<const short8*>(stw + col * STP + 0 * 32 + quad * 8);
    short8 T1 = *reinterpret_cast<const short8*>(stw + col * STP + 1 * 32 + quad * 8);

#pragma unroll
    for (int t = 0; t < 4; ++t) {
        floatx4 c = {0.0f, 0.0f, 0.0f, 0.0f};
        c = __builtin_amdgcn_mfma_f32_16x16x32_bf16(T0, WB[t][0], c, 0, 0, 0);
        c = __builtin_amdgcn_mfma_f32_16x16x32_bf16(T1, WB[t][1], c, 0, 0, 0);
#pragma unroll
        for (int r = 0; r < 4; ++r) {
            float v = fmaxf(c[r] + bBl[t], 0.0f);
            outp[(size_t)(n0 + quad * 4 + r) * D + t * 16 + col] = f2bf(v);
        }
    }
}

// ---------------------------------------------------------------------------
// Fused gather + MLP layer 2 + mean-pool numerator: gather from h1 into the
// wave's LDS tile, MFMA MLP, output tile to LDS (fp32), then the per-block
// segmented reduction over sorted batch[] adds into psum[B,64].
// ---------------------------------------------------------------------------
__global__ __launch_bounds__(256) void g2mlp_pool_kernel(
    const unsigned short* __restrict__ feat,   // h1 (layer-1 output)
    const int*            __restrict__ cnt,
    const unsigned short* __restrict__ bucket,
    const unsigned short* __restrict__ wAb,
    const float*          __restrict__ bA,
    const unsigned short* __restrict__ wBb,
    const float*          __restrict__ bB,
    const int*            __restrict__ batch,  // [N] sorted
    float*                __restrict__ psum)   // [B,64] zero-initialized
{
    __shared__ __align__(16) unsigned short st[4][16 * STP];
    __shared__ float pt[64][D + 1];            // block's 64-node output tile
    __shared__ int   sbatch[64];

    const int tid  = threadIdx.x;
    const int wv   = tid >> 6;
    const int lane = tid & 63;
    const int quad = lane >> 4;
    const int col  = lane & 15;

    const int bn0 = blockIdx.x * 64;           // block's first node
    const int n0  = bn0 + wv * 16;             // wave's first node
    const bool active = (n0 < N_NODES);

    if (tid < 64) {
        int n = bn0 + tid;
        sbatch[tid] = (n < N_NODES) ? batch[n] : -1;
    }

    if (active) {
        float bAl[4], bBl[4];
#pragma unroll
        for (int t = 0; t < 4; ++t) {
            bAl[t] = bA[t * 16 + col];
            bBl[t] = bB[t * 16 + col];
        }

        short8 WA[4][2], WB[4][2];
#pragma unroll
        for (int t = 0; t < 4; ++t)
#pragma unroll
            for (int k = 0; k < 2; ++k) {
                WA[t][k] = *reinterpret_cast<const short8*>(
                    wAb + (t * 16 + col) * D + k * 32 + quad * 8);
                WB[t][k] = *reinterpret_cast<const short8*>(
                    wBb + (t * 16 + col) * D + k * 32 + quad * 8);
            }

        unsigned short* stw = &st[wv][0];

        gather16(feat, cnt, bucket, stw, n0, lane);

        short8 A0 = *reinterpret_cast<const short8*>(stw + col * STP + 0 * 32 + quad * 8);
        short8 A1 = *reinterpret_cast<const short8*>(stw + col * STP + 1 * 32 + quad * 8);

#pragma unroll
        for (int t = 0; t < 4; ++t) {
            floatx4 c = {0.0f, 0.0f, 0.0f, 0.0f};
            c = __builtin_amdgcn_mfma_f32_16x16x32_bf16(A0, WA[t][0], c, 0, 0, 0);
            c = __builtin_amdgcn_mfma_f32_16x16x32_bf16(A1, WA[t][1], c, 0, 0, 0);
#pragma unroll
            for (int r = 0; r < 4; ++r) {
                float v = fmaxf(c[r] + bAl[t], 0.0f);
                stw[(quad * 4 + r) * STP + t * 16 + col] = f2bf(v);
            }
        }

        short8 T0 = *reinterpret_cast<const short8*>(stw + col * STP + 0 * 32 + quad * 8);
        short8 T1 = *reinterpret_cast<const short8*>(stw + col * STP + 1 * 32 + quad * 8);

#pragma unroll
        for (int t = 0; t < 4; ++t) {
            floatx4 c = {0.0f, 0.0f, 0.0f, 0.0f};
            c = __builtin_amdgcn_mfma_f32_16x16x32_bf16(T0, WB[t][0], c, 0, 0, 0);
            c = __builtin_amdgcn_mfma_f32_16x16x32_bf16(T1, WB[t][1], c, 0, 0, 0);
#pragma unroll
            for (int r = 0; r < 4; ++r) {
                float v = fmaxf(c[r] + bBl[t], 0.0f);
                pt[wv * 16 + quad * 4 + r][t * 16 + col] = v;
            }
        }
    } else {
        // inactive wave: zero its tile rows so the reduce sees zeros
#pragma unroll
        for (int r = 0; r < 4; ++r)
            pt[wv * 16 + quad * 4 + r][(lane & 15) * 4 + (lane >> 4)] = 0.0f;
        // fully zero the rows (16 cols per lane-iter)
        for (int c = 0; c < 4; ++c)
#pragma unroll
            for (int r = 0; r < 4; ++r)
                pt[wv * 16 + quad * 4 + r][c * 16 + col] = 0.0f;
    }
    __syncthreads();

    // segmented reduce: thread (q,d) sums rows q*16..q*16+15 of dim d,
    // flushing one atomicAdd per graph run (sorted batch => few runs).
    int q = tid >> 6;
    int d = tid & 63;
    float acc = 0.0f;
    int curg = sbatch[q * 16];
#pragma unroll
    for (int r = 0; r < 16; ++r) {
        int row = q * 16 + r;
        int g = sbatch[row];
        float v = pt[row][d];
        if (g != curg) {
            if (curg >= 0) atomicAdd(&psum[curg * D + d], acc);
            acc = 0.0f;
            curg = g;
        }
        acc += v;
    }
    if (curg >= 0) atomicAdd(&psum[curg * D + d], acc);
}

// ---------------------------------------------------------------------------
// Head: mean from psum + counts, single-step LSTM + FC + softmax.
// ---------------------------------------------------------------------------
__device__ __forceinline__ int lower_bound_dev(const int* a, int n, int v)
{
    int lo = 0, hi = n;
    while (lo < hi) {
        int m = (lo + hi) >> 1;
        if (a[m] < v) lo = m + 1; else hi = m;
    }
    return lo;
}

__device__ __forceinline__ float sigmoidf_(float x) { return 1.0f / (1.0f + expf(-x)); }

__global__ __launch_bounds__(512) void head_kernel(
    const float* __restrict__ psum,   // [B,64] pooled sums
    const int*   __restrict__ batch,  // [N]
    const float* __restrict__ w_ih,
    const float* __restrict__ w_hh,
    const float* __restrict__ b_ih,
    const float* __restrict__ b_hh,
    const float* __restrict__ fc_w,
    const float* __restrict__ fc_b,
    const float* __restrict__ h0,
    const float* __restrict__ c0,
    float*       __restrict__ out_probs,
    float*       __restrict__ out_h1,
    float*       __restrict__ out_c1)
{
    int b = blockIdx.x;
    int j = threadIdx.x;

    __shared__ float sp[D];
    __shared__ float sh[HL];
    __shared__ float gates[4 * HL];
    __shared__ float sh1[HL];
    __shared__ float slog[OUT];

    if (j < D) {
        int start = lower_bound_dev(batch, N_NODES, b);
        int end   = lower_bound_dev(batch, N_NODES, b + 1);
        sp[j] = psum[b * D + j] / fmaxf((float)(end - start), 1.0f);
    } else if (j < D + HL) {
        sh[j - D] = h0[b * HL + (j - D)];
    }
    __syncthreads();

    {
        float acc = b_ih[j] + b_hh[j];
#pragma unroll
        for (int k = 0; k < D; ++k)  acc = fmaf(sp[k], w_ih[j * D + k], acc);
#pragma unroll
        for (int k = 0; k < HL; ++k) acc = fmaf(sh[k], w_hh[j * HL + k], acc);
        gates[j] = acc;
    }
    __syncthreads();

    if (j < HL) {
        float ig = gates[j];
        float fg = gates[HL + j];
        float gg = gates[2 * HL + j];
        float og = gates[3 * HL + j];
        float c  = sigmoidf_(fg) * c0[b * HL + j] + sigmoidf_(ig) * tanhf(gg);
        float hv = sigmoidf_(og) * tanhf(c);
        out_c1[b * HL + j] = c;
        out_h1[b * HL + j] = hv;
        sh1[j] = hv;
    }
    __syncthreads();

    if (j < OUT) {
        float a = fc_b[j];
#pragma unroll
        for (int k = 0; k < HL; ++k) a = fmaf(sh1[k], fc_w[j * HL + k], a);
        slog[j] = a;
    }
    __syncthreads();

    if (j < OUT) {
        float m = -1e30f;
#pragma unroll
        for (int k = 0; k < OUT; ++k) m = fmaxf(m, slog[k]);
        float s = 0.0f;
#pragma unroll
        for (int k = 0; k < OUT; ++k) s += expf(slog[k] - m);
        out_probs[b * OUT + j] = expf(slog[j] - m) / s;
    }
}

// ---------------------------------------------------------------------------
extern "C" void kernel_launch(void* const* d_in, const int* in_sizes, int n_in,
                              void* d_out, int out_size, void* d_ws, size_t ws_size,
                              hipStream_t stream)
{
    const float* x     = (const float*)d_in[0];
    const int*   ei    = (const int*)  d_in[1];
    const int*   batch = (const int*)  d_in[2];
    const float* w1    = (const float*)d_in[3];
    const float* b1    = (const float*)d_in[4];
    const float* w2    = (const float*)d_in[5];
    const float* b2    = (const float*)d_in[6];
    const float* w3    = (const float*)d_in[7];
    const float* b3    = (const float*)d_in[8];
    const float* w4    = (const float*)d_in[9];
    const float* b4    = (const float*)d_in[10];
    const float* w_ih  = (const float*)d_in[11];
    const float* w_hh  = (const float*)d_in[12];
    const float* b_ih  = (const float*)d_in[13];
    const float* b_hh  = (const float*)d_in[14];
    const float* fc_w  = (const float*)d_in[15];
    const float* fc_b  = (const float*)d_in[16];
    const float* h0    = (const float*)d_in[17];
    const float* c0    = (const float*)d_in[18];

    // workspace layout (~22 MB); xb/h1 have N+16 rows (row ZROW = 0)
    // (g slot retained for layout stability; no longer written/read)
    const size_t NR = (size_t)N_NODES + 16;
    int* bincnt = (int*)d_ws;                                 // 256 ints
    int* cnt    = bincnt + 256;                               // N ints
    unsigned* binbuf = (unsigned*)(cnt + N_NODES);            // BINS*BCAP
    unsigned short* bucket = (unsigned short*)(binbuf + (size_t)BINS * BCAP);
    unsigned short* xb = bucket + (size_t)N_NODES * CAP;      // [NR,64] bf16
    unsigned short* g  = xb + NR * D;                         // [NR,64] (unused)
    unsigned short* h1 = g  + NR * D;                         // [NR,64] mlp1 out
    unsigned short* wb = h1 + NR * D;                         // 4 x [64,64] bf16
    float* psum = (float*)(wb + 4 * D * D);                   // [B,64]
    (void)g;

    float* out_probs = (float*)d_out;
    float* out_h1    = out_probs + B * OUT;
    float* out_c1    = out_h1 + B * HL;

    const int mb = (N_NODES / 16 + 3) / 4;           // 782

    // ---- bincnt zero (1 KB) + fused prologue (binA || cvt || init) ----
    hipMemsetAsync(bincnt, 0, 256 * sizeof(int), stream);
    fused_pro_kernel<<<AB + CB + 1, 256, 0, stream>>>(
        ei, bincnt, binbuf, x, xb, w1, w2, w3, w4, wb, h1, psum);

    // ---- adjacency build phase B ----
    binB_kernel<<<BINS, 256, 0, stream>>>(bincnt, binbuf, cnt, bucket);

    // ---- layer 1 (fused gather + MLP) ----
    gmlp_kernel<<<mb, 256, 0, stream>>>(xb, cnt, bucket, wb, b1, wb + 4096, b2, h1);

    // ---- layer 2 (fused gather + MLP + pool) ----
    g2mlp_pool_kernel<<<mb, 256, 0, stream>>>(h1, cnt, bucket,
                                              wb + 8192, b3, wb + 12288, b4,
                                              batch, psum);

    // ---- head ----
    head_kernel<<<B, 512, 0, stream>>>(psum, batch, w_ih, w_hh, b_ih, b_hh,
                                       fc_w, fc_b, h0, c0,
                                       out_probs, out_h1, out_c1);
}